// Round 12
// baseline (136.149 us; speedup 1.0000x reference)
//
#include <hip/hip_runtime.h>
#include <math.h>

#define NRAYS 8192
#define T 128
#define H 128
#define SHD 16

using short8 = __attribute__((ext_vector_type(8))) short;
using f32x4  = __attribute__((ext_vector_type(4))) float;
using f32x2  = __attribute__((ext_vector_type(2))) float;

__device__ __forceinline__ float fexp(float x) {
  return exp2f(x * 1.44269504088896341f);
}
__device__ __forceinline__ float softplus_f(float x) {
  return fmaxf(x, 0.f) + 0.693147180559945309f * log2f(1.f + fexp(-fabsf(x)));
}
__device__ __forceinline__ float sigmoid_f(float x) {
  return __builtin_amdgcn_rcpf(1.f + fexp(-x));
}

// RNE float->bf16 (preprocess only)
__device__ __forceinline__ unsigned f2bf(float f) {
  unsigned u = __float_as_uint(f);
  return (u + 0x7fffu + ((u >> 16) & 1u)) >> 16;
}

// RNE bf16 pack of a float pair: single VALU op (v_cvt_pk_bf16_f32, gfx950)
__device__ __forceinline__ unsigned pk2(f32x2 h) {
  unsigned r;
  asm("v_cvt_pk_bf16_f32 %0, %1, %2" : "=v"(r) : "v"(h[0]), "v"(h[1]));
  return r;
}

// ---- preprocess (R1/R11 version — cheap) ----
// w2t: bf16 W2^T, XOR-swizzled: w2t[n*128 + p], octet o=(p>>3)^(n&7), k=o*8+(p&7)
// woutf[(kk*64+L)*8+j]: epilogue A-frag; rayp_all[r][8] = AABB + SH scalars.
__global__ void preprocess(const float* __restrict__ W2, const float* __restrict__ Wd,
                           const float* __restrict__ Wc, const float* __restrict__ bc,
                           const float* __restrict__ origins, const float* __restrict__ dirs,
                           unsigned short* __restrict__ w2t,
                           unsigned short* __restrict__ woutf,
                           float* __restrict__ rayp_all) {
  const int t = blockIdx.x * 256 + threadIdx.x;
  if (t < 16384) {
    const int n = t >> 7, p = t & 127;
    const int o = (p >> 3) ^ (n & 7);
    const int k = o * 8 + (p & 7);
    w2t[t] = (unsigned short)f2bf(W2[k * 128 + n]);
  }
  if (t < 2048) {
    const int kk = t >> 9, L = (t >> 3) & 63, j = t & 7;
    const int c = L & 15, g = L >> 4;
    const int k = kk * 32 + g * 8 + j;
    float v = 0.f;
    if (c == 0) v = Wd[k];
    else if (c < 4) v = Wc[k * 3 + (c - 1)];
    woutf[t] = (unsigned short)f2bf(v);
  }
  if (t < NRAYS) {
    const float ox = origins[t*3+0], oy = origins[t*3+1], oz = origins[t*3+2];
    const float dx = dirs[t*3+0],  dy = dirs[t*3+1],  dz = dirs[t*3+2];
    const float ix = 1.f/dx, iy = 1.f/dy, iz = 1.f/dz;
    const float t1x = (-1.f-ox)*ix, t2x = (1.f-ox)*ix;
    const float t1y = (-1.f-oy)*iy, t2y = (1.f-oy)*iy;
    const float t1z = (-1.f-oz)*iz, t2z = (1.f-oz)*iz;
    float tnear = fmaxf(fmaxf(fminf(t1x,t2x), fminf(t1y,t2y)), fminf(t1z,t2z));
    tnear = fmaxf(tnear, 0.f);
    const float tfar = fminf(fminf(fmaxf(t1x,t2x), fmaxf(t1y,t2y)), fmaxf(t1z,t2z));
    const bool  active = tfar > tnear;
    const float tfar_c = fmaxf(tfar, tnear + 1e-3f);
    const float dnorm = sqrtf(dx*dx + dy*dy + dz*dz);
    const float nx = dx/dnorm, ny = dy/dnorm, nz = dz/dnorm;
    const float x2 = nx*nx, y2 = ny*ny, z2 = nz*nz;
    const float xy = nx*ny, yz = ny*nz, xz = nx*nz;
    float ynm[16];
    ynm[0]  = 0.282094791773878f;
    ynm[1]  = -0.48860251190292f*ny;
    ynm[2]  = 0.48860251190292f*nz;
    ynm[3]  = -0.48860251190292f*nx;
    ynm[4]  = 1.0925484305920792f*xy;
    ynm[5]  = -1.0925484305920792f*yz;
    ynm[6]  = 0.94617469575756f*z2 - 0.31539156525252f;
    ynm[7]  = -1.0925484305920792f*xz;
    ynm[8]  = 0.5462742152960396f*(x2-y2);
    ynm[9]  = 0.5900435899266435f*ny*(-3.f*x2+y2);
    ynm[10] = 2.8906114426405538f*xy*nz;
    ynm[11] = 0.4570457994644658f*ny*(1.f-5.f*z2);
    ynm[12] = 0.3731763325901154f*nz*(5.f*z2-3.f);
    ynm[13] = 0.4570457994644658f*nx*(1.f-5.f*z2);
    ynm[14] = 1.445305721320277f*nz*(x2-y2);
    ynm[15] = 0.5900435899266435f*nx*(-x2+3.f*y2);
    float cp0 = bc[0], cp1 = bc[1], cp2 = bc[2];
    #pragma unroll
    for (int s = 0; s < SHD; ++s) {
      cp0 = fmaf(ynm[s], Wc[(H+s)*3+0], cp0);
      cp1 = fmaf(ynm[s], Wc[(H+s)*3+1], cp1);
      cp2 = fmaf(ynm[s], Wc[(H+s)*3+2], cp2);
    }
    rayp_all[t*8+0] = tfar_c;
    rayp_all[t*8+1] = dnorm;
    rayp_all[t*8+2] = active ? 1.f : 0.f;
    rayp_all[t*8+3] = cp0;
    rayp_all[t*8+4] = cp1;
    rayp_all[t*8+5] = cp2;
    rayp_all[t*8+6] = tnear;
    rayp_all[t*8+7] = 0.f;
  }
}

// TWO rays per 512-thread block: waves 0-3 -> ray 2b, waves 4-7 -> ray 2b+1.
// One shared W2 staging per block halves total L2->LDS staging traffic
// (256 MB -> 128 MB) and halves block count — the only untouched knob after
// R5-R11 measured VALU/LDS-op/occupancy changes null at fixed staging.
// Epilogue: R11's disjoint-slab idea, kk-parity double-buffered (2x640
// shorts/wave; 8 waves = 20 KB inside dead Bs). In-order LDS per wave
// guarantees read(kk) completes before write(kk+2) reuses its buffer.
// LDS: Bs 32768 + per-ray arrays 4096 + wred/wtot 80 ~= 36.9 KB.
// Regs: ~56 VGPR + 64 AGPR = 120 -> 4 waves/SIMD -> 2 blocks/CU (4 rays
// resident, same as R11, with half the staging).
#define SLAB_W(kk, sb) { \
  { const f32x4 a = acc[tm][(kk)*2+0]; \
    const f32x2 h01 = __builtin_elementwise_max((f32x2){a[0],a[1]}, zero2); \
    const f32x2 h23 = __builtin_elementwise_max((f32x2){a[2],a[3]}, zero2); \
    *(uint2*)&(sb)[c*40 + g*4] = make_uint2(pk2(h01), pk2(h23)); } \
  { const f32x4 a = acc[tm][(kk)*2+1]; \
    const f32x2 h01 = __builtin_elementwise_max((f32x2){a[0],a[1]}, zero2); \
    const f32x2 h23 = __builtin_elementwise_max((f32x2){a[2],a[3]}, zero2); \
    *(uint2*)&(sb)[c*40 + 16 + g*4] = make_uint2(pk2(h01), pk2(h23)); } }

__global__ __launch_bounds__(512, 2) void nerf_render(
    const float* __restrict__ origins, const float* __restrict__ dirs,
    const float* __restrict__ u, const float* __restrict__ W1,
    const float* __restrict__ b1, const float* __restrict__ b2,
    const float* __restrict__ bd, const unsigned short* __restrict__ w2t,
    const unsigned short* __restrict__ woutf, const float* __restrict__ rayp_all,
    float* __restrict__ out)
{
  const int tid = threadIdx.x;
  const int L = tid & 63;
  const int w = tid >> 6;        // 0..7
  const int wr = w & 3;          // wave within its ray
  const int r  = w >> 2;         // which ray half this wave serves
  const int g = L >> 4;
  const int c = L & 15;

  __shared__ __align__(16) short Bs[16384];       // swizzled W2^T; aliased post-barrier
  __shared__ __align__(16) float baseA[2][H];     // per-ray affine layer-1 SoA
  __shared__ __align__(16) float slopeA[2][H];
  __shared__ __align__(16) float ts_s[2][T];
  __shared__ __align__(16) float mask_s[2][T];
  __shared__ float wred[2][2][4];
  __shared__ float wtot[2][2];

  // ---- stage W2 (shared by both rays): 512 thr x 4 float4 = 32 KB ----
  {
    const float4* src = (const float4*)w2t;
    float4* dst = (float4*)Bs;
    #pragma unroll
    for (int i = 0; i < 4; ++i) dst[tid + i * 512] = src[tid + i * 512];
  }

  // ---- per-sample setup: tid<256 covers both rays (r2 = tid>>7) ----
  if (tid < 256) {
    const int r2 = tid >> 7, tl = tid & 127;
    const int ray2 = blockIdx.x * 2 + r2;
    const float tfar_c = rayp_all[ray2*8+0];
    const float actf   = rayp_all[ray2*8+2];
    const float tnear  = rayp_all[ray2*8+6];
    const float ox = origins[ray2*3+0], oy = origins[ray2*3+1], oz = origins[ray2*3+2];
    const float dx = dirs[ray2*3+0],  dy = dirs[ray2*3+1],  dz = dirs[ray2*3+2];
    const bool active = actf != 0.f;
    const float ut = u[ray2*T + tl];
    const float frac = ((float)tl + ut) * (1.f/(float)T);
    const float tt = tnear + (tfar_c - tnear) * frac;
    const float px = fmaf(dx, tt, ox);
    const float py = fmaf(dy, tt, oy);
    const float pz = fmaf(dz, tt, oz);
    ts_s[r2][tl] = tt;
    const bool m = (fabsf(px) <= 1.f) && (fabsf(py) <= 1.f) && (fabsf(pz) <= 1.f) && active;
    mask_s[r2][tl] = m ? 1.f : 0.f;
    const float w0 = W1[tl], w1v = W1[H + tl], w2v = W1[2*H + tl];
    baseA[r2][tl]  = fmaf(ox, w0, fmaf(oy, w1v, fmaf(oz, w2v, b1[tl])));
    slopeA[r2][tl] = fmaf(dx, w0, fmaf(dy, w1v, dz * w2v));
  }

  // ---- acc init = b2 (uniform global reads, L2-hot) ----
  f32x4 acc[2][8];
  #pragma unroll
  for (int mt = 0; mt < 8; ++mt) {
    const float4 bv = *(const float4*)&b2[mt*16 + g*4];
    #pragma unroll
    for (int tm = 0; tm < 2; ++tm) {
      acc[tm][mt][0] = bv.x; acc[tm][mt][1] = bv.y;
      acc[tm][mt][2] = bv.z; acc[tm][mt][3] = bv.w;
    }
  }
  __syncthreads();

  // ---- fused affine-layer1 (packed VALU) + layer2 (MFMA, W2 frags from LDS) ----
  const float t0 = ts_s[r][32*wr + c];
  const float t1 = ts_s[r][32*wr + 16 + c];
  const f32x2 tz0 = {t0, t0}, tz1 = {t1, t1};
  const f32x2 zero2 = {0.f, 0.f};

  #pragma unroll
  for (int ks = 0; ks < 4; ++ks) {
    const int kb = ks*32 + g*8;
    const f32x4 bq0 = *(const f32x4*)&baseA[r][kb];
    const f32x4 bq1 = *(const f32x4*)&baseA[r][kb+4];
    const f32x4 sq0 = *(const f32x4*)&slopeA[r][kb];
    const f32x4 sq1 = *(const f32x4*)&slopeA[r][kb+4];
    const f32x2 b01 = {bq0[0], bq0[1]}, b23 = {bq0[2], bq0[3]};
    const f32x2 b45 = {bq1[0], bq1[1]}, b67 = {bq1[2], bq1[3]};
    const f32x2 s01 = {sq0[0], sq0[1]}, s23 = {sq0[2], sq0[3]};
    const f32x2 s45 = {sq1[0], sq1[1]}, s67 = {sq1[2], sq1[3]};
    const f32x2 a01 = __builtin_elementwise_max(__builtin_elementwise_fma(tz0, s01, b01), zero2);
    const f32x2 a23 = __builtin_elementwise_max(__builtin_elementwise_fma(tz0, s23, b23), zero2);
    const f32x2 a45 = __builtin_elementwise_max(__builtin_elementwise_fma(tz0, s45, b45), zero2);
    const f32x2 a67 = __builtin_elementwise_max(__builtin_elementwise_fma(tz0, s67, b67), zero2);
    const f32x2 e01 = __builtin_elementwise_max(__builtin_elementwise_fma(tz1, s01, b01), zero2);
    const f32x2 e23 = __builtin_elementwise_max(__builtin_elementwise_fma(tz1, s23, b23), zero2);
    const f32x2 e45 = __builtin_elementwise_max(__builtin_elementwise_fma(tz1, s45, b45), zero2);
    const f32x2 e67 = __builtin_elementwise_max(__builtin_elementwise_fma(tz1, s67, b67), zero2);
    union U { uint4 u; short8 s; } A0, A1;
    A0.u = make_uint4(pk2(a01), pk2(a23), pk2(a45), pk2(a67));
    A1.u = make_uint4(pk2(e01), pk2(e23), pk2(e45), pk2(e67));
    const int swb = ((ks*4 + g) ^ (c & 7)) * 8;   // swizzled octet (conflict-free)
    #pragma unroll
    for (int mt = 0; mt < 8; ++mt) {
      const short8 wf = *(const short8*)&Bs[(mt*16 + c)*128 + swb];
      acc[0][mt] = __builtin_amdgcn_mfma_f32_16x16x32_bf16(wf, A0.s, acc[0][mt], 0, 0, 0);
      acc[1][mt] = __builtin_amdgcn_mfma_f32_16x16x32_bf16(wf, A1.s, acc[1][mt], 0, 0, 0);
    }
  }
  __syncthreads();   // all waves done with Bs -> safe to alias SredP/As2 onto it
  float4* SredP = (float4*)Bs;                // bytes [0, 4096): 2 rays x 128 samples
  short*  As2   = Bs + 2048;                  // bytes [4096, 24576): 8 waves x 2x640 shorts

  // ---- epilogue: kk-parity double-buffered slab -> MFMA dot with Wout ----
  short* sb0 = As2 + w * 1280;        // even kk
  short* sb1 = sb0 + 640;             // odd kk
  short8 wa[4];
  #pragma unroll
  for (int kk = 0; kk < 4; ++kk)
    wa[kk] = *(const short8*)&woutf[(kk*64 + L)*8];   // global, L2-hot

  #pragma unroll
  for (int tm = 0; tm < 2; ++tm) {
    f32x4 oacc;
    oacc[0] = 0.f; oacc[1] = 0.f; oacc[2] = 0.f; oacc[3] = 0.f;
    SLAB_W(0, sb0)
    SLAB_W(1, sb1)
    { const short8 h = *(const short8*)&sb0[c*40 + g*8];
      oacc = __builtin_amdgcn_mfma_f32_16x16x32_bf16(wa[0], h, oacc, 0, 0, 0); }
    SLAB_W(2, sb0)
    { const short8 h = *(const short8*)&sb1[c*40 + g*8];
      oacc = __builtin_amdgcn_mfma_f32_16x16x32_bf16(wa[1], h, oacc, 0, 0, 0); }
    SLAB_W(3, sb1)
    { const short8 h = *(const short8*)&sb0[c*40 + g*8];
      oacc = __builtin_amdgcn_mfma_f32_16x16x32_bf16(wa[2], h, oacc, 0, 0, 0); }
    { const short8 h = *(const short8*)&sb1[c*40 + g*8];
      oacc = __builtin_amdgcn_mfma_f32_16x16x32_bf16(wa[3], h, oacc, 0, 0, 0); }
    if (g == 0)   // lane holds {sigma,c0,c1,c2} for its ray's sample 32wr+16tm+c
      SredP[r*128 + 32*wr + 16*tm + c] = make_float4(oacc[0], oacc[1], oacc[2], oacc[3]);
  }
  __syncthreads();

  // ---- per-sample activations + transmittance: tid<256, r2 = tid>>7 ----
  float sd = 0.f, cc0 = 0.f, cc1 = 0.f, cc2 = 0.f;
  if (tid < 256) {
    const int r2 = tid >> 7, s = tid & 127;
    const int ray2 = blockIdx.x * 2 + r2;
    const float4 sv = SredP[r2*128 + s];
    const float mk = mask_s[r2][s];
    const float dnorm  = rayp_all[ray2*8+1];
    const float cpo0   = rayp_all[ray2*8+3];
    const float cpo1   = rayp_all[ray2*8+4];
    const float cpo2   = rayp_all[ray2*8+5];
    const float tfar_c = rayp_all[ray2*8+0];
    const float sigma = softplus_f(sv.x + bd[0]) * mk;
    cc0 = mk * sigmoid_f(sv.y + cpo0);
    cc1 = mk * sigmoid_f(sv.z + cpo1);
    cc2 = mk * sigmoid_f(sv.w + cpo2);
    const float tt = ts_s[r2][s];
    const float tnext = (s < T-1) ? ts_s[r2][s + 1] : tfar_c * 10.f;
    sd = sigma * (tnext - tt) * dnorm;
  }

  // ---- inclusive scan: in-wave shfl + per-ray cross-wave stitch ----
  float val = sd;
  #pragma unroll
  for (int off = 1; off < 64; off <<= 1) {
    const float tmp = __shfl_up(val, off);
    if (L >= off) val += tmp;
  }
  if (tid < 256 && L == 63) wtot[tid >> 7][(tid >> 6) & 1] = val;
  __syncthreads();

  // ---- weights + per-ray reduction ----
  float wgt = 0.f, wcx = 0.f, wcy = 0.f, wcz = 0.f;
  if (tid < 256) {
    const float csum = val + (((tid >> 6) & 1) ? wtot[tid >> 7][0] : 0.f);
    wgt = fexp(sd - csum) - fexp(-csum);
    wcx = wgt * cc0; wcy = wgt * cc1; wcz = wgt * cc2;
  }
  #pragma unroll
  for (int mm = 32; mm >= 1; mm >>= 1) {
    wgt += __shfl_xor(wgt, mm);
    wcx += __shfl_xor(wcx, mm);
    wcy += __shfl_xor(wcy, mm);
    wcz += __shfl_xor(wcz, mm);
  }
  if (tid < 256 && L == 0) {
    float* wr4 = wred[tid >> 7][(tid >> 6) & 1];
    wr4[0] = wgt; wr4[1] = wcx; wr4[2] = wcy; wr4[3] = wcz;
  }
  __syncthreads();
  if (tid < 2) {
    const int ray2 = blockIdx.x * 2 + tid;
    const float aw = wred[tid][0][0] + wred[tid][1][0];
    const float o0 = wred[tid][0][1] + wred[tid][1][1];
    const float o1 = wred[tid][0][2] + wred[tid][1][2];
    const float o2 = wred[tid][0][3] + wred[tid][1][3];
    const bool act = rayp_all[ray2*8+2] != 0.f;
    float4 o;
    o.x = act ? o0 : 0.f;
    o.y = act ? o1 : 0.f;
    o.z = act ? o2 : 0.f;
    o.w = act ? aw : 0.f;
    *(float4*)&out[ray2*4] = o;
  }
}

extern "C" void kernel_launch(void* const* d_in, const int* in_sizes, int n_in,
                              void* d_out, int out_size, void* d_ws, size_t ws_size,
                              hipStream_t stream) {
  const float* origins = (const float*)d_in[0];
  const float* dirs    = (const float*)d_in[1];
  const float* u       = (const float*)d_in[2];
  const float* W1      = (const float*)d_in[3];
  const float* b1      = (const float*)d_in[4];
  const float* W2      = (const float*)d_in[5];
  const float* b2      = (const float*)d_in[6];
  const float* Wd      = (const float*)d_in[7];
  const float* bd      = (const float*)d_in[8];
  const float* Wc      = (const float*)d_in[9];
  const float* bc      = (const float*)d_in[10];

  unsigned short* w2t      = (unsigned short*)d_ws;
  unsigned short* woutf    = (unsigned short*)((char*)d_ws + 32768);
  float*          rayp_all = (float*)((char*)d_ws + 36864);

  preprocess<<<64, 256, 0, stream>>>(W2, Wd, Wc, bc, origins, dirs,
                                     w2t, woutf, rayp_all);
  nerf_render<<<NRAYS/2, 512, 0, stream>>>(origins, dirs, u, W1, b1, b2, bd,
                                           w2t, woutf, rayp_all, (float*)d_out);
}